// Round 7
// baseline (173.210 us; speedup 1.0000x reference)
//
#include <hip/hip_runtime.h>

typedef __attribute__((ext_vector_type(4)))  float f32x4;
typedef __attribute__((ext_vector_type(16))) float f32x16;
typedef __attribute__((ext_vector_type(8)))  short short8;
typedef __attribute__((ext_vector_type(4)))  unsigned short u16x4;

// float -> bf16, round-to-nearest-even
static __device__ __forceinline__ unsigned short f2bf(float f) {
    unsigned int u = __float_as_uint(f);
    unsigned int r = (u + 0x7FFFu + ((u >> 16) & 1u)) >> 16;
    return (unsigned short)r;
}

// lgkm-drain + raw barrier (does NOT drain vmcnt: keeps global prefetches in flight)
static __device__ __forceinline__ void block_sync_lds() {
    asm volatile("s_waitcnt lgkmcnt(0)" ::: "memory");
    __builtin_amdgcn_s_barrier();
    asm volatile("" ::: "memory");
}

#if __has_builtin(__builtin_amdgcn_exp2f)
#define EXP2(x) __builtin_amdgcn_exp2f(x)
#else
#define EXP2(x) exp2f(x)
#endif

// 32^-0.5 * log2(e): q-scale with exp2 conversion folded in
#define SCALE2Q 0.25503487756f

// ---------------------------------------------------------------------------
// Kernel 1: pack weights to bf16. W[320][256]: rows 0..31 = scale2q*w_qk(q),
// rows 32..63 = w_qk(k), rows 64..319 = w_v.
// ---------------------------------------------------------------------------
__global__ void prep_w_kernel(const float* __restrict__ wqk,
                              const float* __restrict__ wv,
                              unsigned short* __restrict__ W) {
    int idx = blockIdx.x * 256 + threadIdx.x;
    int o = idx >> 8, c = idx & 255;
    float v;
    if (o < 64) { v = wqk[o * 256 + c]; if (o < 32) v *= SCALE2Q; }
    else        { v = wv[(o - 64) * 256 + c]; }
    W[idx] = f2bf(v);
}

// ---------------------------------------------------------------------------
// Kernel 2: xT[b][s][c] = bf16(x[b][c][s]).  64x64 tiles via LDS.
// ---------------------------------------------------------------------------
__global__ __launch_bounds__(256) void transpose_kernel(
        const float* __restrict__ x, unsigned short* __restrict__ xT) {
    __shared__ unsigned short tile[64][66];
    int b = blockIdx.x & 7;
    int rem = blockIdx.x >> 3;
    int ct = rem >> 6, st = rem & 63;
    int s0 = st * 64, c0 = ct * 64;
    int tid = threadIdx.x;
    int ss = tid & 63, cq = tid >> 6;
#pragma unroll
    for (int p = 0; p < 16; ++p) {
        int cc = p * 4 + cq;
        float v = x[(size_t)(b * 256 + c0 + cc) * 4096 + s0 + ss];
        tile[ss][cc] = f2bf(v);
    }
    __syncthreads();
#pragma unroll
    for (int p = 0; p < 8; ++p) {
        int idx = p * 256 + tid;
        int sr = idx >> 5, jj = idx & 31;
        unsigned int val = *(const unsigned int*)&tile[sr][jj * 2];
        *(unsigned int*)(xT + (size_t)(b * 4096 + s0 + sr) * 256 + c0 + jj * 2) = val;
    }
}

// ---------------------------------------------------------------------------
// Kernel 3: projection GEMM (MFMA 16x16x32, no LDS).
// ---------------------------------------------------------------------------
__global__ __launch_bounds__(256) void proj_kernel(
        const unsigned short* __restrict__ W,    // [320][256]
        const unsigned short* __restrict__ xT,   // [8][4096][256]
        unsigned short* __restrict__ qkT,        // [8][4096][64]
        unsigned short* __restrict__ vbuf) {     // [8][256][4096]
    const int b  = blockIdx.x & 7;
    const int sb = blockIdx.x >> 3;
    const int s0 = sb * 64;
    const int tid = threadIdx.x;
    const int w = tid >> 6, l = tid & 63;
    const int lg = l >> 4, ll = l & 15;
    const size_t xbase = (size_t)b * 4096 * 256;

    f32x4 acc[5][4];
#pragma unroll
    for (int ot = 0; ot < 5; ++ot)
#pragma unroll
        for (int st = 0; st < 4; ++st) acc[ot][st] = (f32x4)0.0f;

    for (int k0 = 0; k0 < 256; k0 += 32) {
        short8 bf[4], af[5];
#pragma unroll
        for (int st = 0; st < 4; ++st)
            bf[st] = *(const short8*)(xT + xbase + (size_t)(s0 + st * 16 + ll) * 256 + k0 + lg * 8);
#pragma unroll
        for (int ot = 0; ot < 5; ++ot)
            af[ot] = *(const short8*)(W + (size_t)(80 * w + ot * 16 + ll) * 256 + k0 + lg * 8);
#pragma unroll
        for (int ot = 0; ot < 5; ++ot)
#pragma unroll
            for (int st = 0; st < 4; ++st)
                acc[ot][st] = __builtin_amdgcn_mfma_f32_16x16x32_bf16(af[ot], bf[st], acc[ot][st], 0, 0, 0);
    }
#pragma unroll
    for (int ot = 0; ot < 5; ++ot) {
        int o0 = 80 * w + ot * 16 + lg * 4;
#pragma unroll
        for (int st = 0; st < 4; ++st) {
            int s = s0 + st * 16 + ll;
            if (o0 < 64) {
                u16x4 pk;
#pragma unroll
                for (int i = 0; i < 4; ++i) pk[i] = f2bf(acc[ot][st][i]);
                *(u16x4*)(qkT + (size_t)b * 4096 * 64 + (size_t)s * 64 + o0) = pk;
            } else {
#pragma unroll
                for (int i = 0; i < 4; ++i)
                    vbuf[(size_t)b * 256 * 4096 + (size_t)(o0 - 64 + i) * 4096 + s] = f2bf(acc[ot][st][i]);
            }
        }
    }
}

// ---------------------------------------------------------------------------
// Kernel 4: attention. grid 512 = 8 b x 32 q-tiles x 2 ch-halves; 512 thr.
// 2 blocks/CU. KVBLK=128 (32 phases). Waves 0-3 producers (swapped QK via
// mfma_32x32x16(K,Q), raw v_exp_f32, cvt_pk, ds_write_b64); waves 4-7
// consumers (32 ch each, 32 ds_read_b128 + 32 MFMA per phase, setprio).
// P double-buffered in LDS [buf][kchunk16][q128][8key]; one lgkm-only
// barrier per phase. K and V register-buffered in halves (A/B) so VGPR<=128.
// ---------------------------------------------------------------------------
__global__ __launch_bounds__(512, 4) void attn_kernel(
        const unsigned short* __restrict__ qkT,  // [8][4096][64] (q|k)
        const unsigned short* __restrict__ vbuf, // [8][256][4096]
        const float* __restrict__ x,             // [8][256][4096]
        const float* __restrict__ gamma,
        float* __restrict__ out) {
    __shared__ unsigned short p_lds[2][16][128][8];  // 64 KiB
    __shared__ float lsum_lds[128];

    const int b     = blockIdx.x & 7;        // batch == XCD (L2 pinning)
    const int sb    = (blockIdx.x >> 3) & 31;
    const int chalf = blockIdx.x >> 8;       // 0/1: channel half
    const int s0    = sb * 128;
    const int tid = threadIdx.x;
    const int w   = tid >> 6;                // 0..7
    const int l   = tid & 63;
    const int l5  = l >> 5, l31 = l & 31;

    const size_t qk_base = (size_t)b * 4096 * 64;
    const size_t bx_base = (size_t)b * 256 * 4096;

    if (w < 4) {
        // ============ PRODUCER: q-rows [s0+32w, +32), 128 keys/phase ========
        const unsigned short* kb = qkT + qk_base + 32;     // k-half of rows
        const int q = 32 * w + l31;                        // block-local q
        const unsigned short* qrow = qkT + qk_base + (size_t)(s0 + q) * 64;
        short8 qf0 = *(const short8*)(qrow + 8 * l5);      // latent 0..15
        short8 qf1 = *(const short8*)(qrow + 16 + 8 * l5); // latent 16..31
        short8 kfA[2][2], kfB[2][2];
#pragma unroll
        for (int kt = 0; kt < 2; ++kt)
#pragma unroll
            for (int h = 0; h < 2; ++h) {
                kfA[kt][h] = *(const short8*)(kb + (size_t)(32 * kt + l31) * 64 + 16 * h + 8 * l5);
                kfB[kt][h] = *(const short8*)(kb + (size_t)(64 + 32 * kt + l31) * 64 + 16 * h + 8 * l5);
            }
        float psum = 0.f;
        const f32x16 zero16 = (f32x16)0.0f;

#define PWRITE(DD, KTG, PB)                                                    \
        _Pragma("unroll") for (int rq = 0; rq < 4; ++rq) {                     \
            float p0 = EXP2((DD)[4 * rq + 0]);                                 \
            float p1 = EXP2((DD)[4 * rq + 1]);                                 \
            float p2 = EXP2((DD)[4 * rq + 2]);                                 \
            float p3 = EXP2((DD)[4 * rq + 3]);                                 \
            psum += (p0 + p1) + (p2 + p3);                                     \
            unsigned int pw0, pw1;                                             \
            asm("v_cvt_pk_bf16_f32 %0, %1, %2" : "=v"(pw0) : "v"(p0), "v"(p1));\
            asm("v_cvt_pk_bf16_f32 %0, %1, %2" : "=v"(pw1) : "v"(p2), "v"(p3));\
            uint2 pv_; pv_.x = pw0; pv_.y = pw1;                               \
            *(uint2*)((char*)&p_lds[PB][rq + 4 * (KTG)][q][0] + 8 * l5) = pv_; \
        }

        for (int t = 0; t < 32; ++t) {
            const int pb = t & 1;
            const int tn = (t < 31) ? (t + 1) * 128 : 0;
            // half A: key tiles 0,1 (keys 0..63 of phase)
            {
                f32x16 dd0 = __builtin_amdgcn_mfma_f32_32x32x16_bf16(kfA[0][0], qf0, zero16, 0, 0, 0);
                dd0 = __builtin_amdgcn_mfma_f32_32x32x16_bf16(kfA[0][1], qf1, dd0, 0, 0, 0);
                f32x16 dd1 = __builtin_amdgcn_mfma_f32_32x32x16_bf16(kfA[1][0], qf0, zero16, 0, 0, 0);
                dd1 = __builtin_amdgcn_mfma_f32_32x32x16_bf16(kfA[1][1], qf1, dd1, 0, 0, 0);
#pragma unroll
                for (int kt = 0; kt < 2; ++kt)
#pragma unroll
                    for (int h = 0; h < 2; ++h)
                        kfA[kt][h] = *(const short8*)(kb + (size_t)(tn + 32 * kt + l31) * 64 + 16 * h + 8 * l5);
                PWRITE(dd0, 0, pb)
                PWRITE(dd1, 1, pb)
            }
            // half B: key tiles 2,3 (keys 64..127 of phase)
            {
                f32x16 dd0 = __builtin_amdgcn_mfma_f32_32x32x16_bf16(kfB[0][0], qf0, zero16, 0, 0, 0);
                dd0 = __builtin_amdgcn_mfma_f32_32x32x16_bf16(kfB[0][1], qf1, dd0, 0, 0, 0);
                f32x16 dd1 = __builtin_amdgcn_mfma_f32_32x32x16_bf16(kfB[1][0], qf0, zero16, 0, 0, 0);
                dd1 = __builtin_amdgcn_mfma_f32_32x32x16_bf16(kfB[1][1], qf1, dd1, 0, 0, 0);
#pragma unroll
                for (int kt = 0; kt < 2; ++kt)
#pragma unroll
                    for (int h = 0; h < 2; ++h)
                        kfB[kt][h] = *(const short8*)(kb + (size_t)(tn + 64 + 32 * kt + l31) * 64 + 16 * h + 8 * l5);
                PWRITE(dd0, 2, pb)
                PWRITE(dd1, 3, pb)
            }
            block_sync_lds();
        }
#undef PWRITE
        // lane covers 64 of q's 128 keys per phase; partner lane is l^32
        psum += __shfl_xor(psum, 32);
        if (l5 == 0) lsum_lds[q] = psum;
        __syncthreads();                       // matches consumers' final sync
    } else {
        // ============ CONSUMER: channel 128*chalf + 32*(w-4) + l31 ==========
        const int ch = 128 * chalf + 32 * (w - 4) + l31;
        const unsigned short* vrow = vbuf + bx_base + (size_t)ch * 4096;
        f32x16 acc[4];
#pragma unroll
        for (int st = 0; st < 4; ++st) acc[st] = (f32x16)0.0f;
        short8 vfA[4], vfB[4];
#pragma unroll
        for (int ks = 0; ks < 4; ++ks)
            vfA[ks] = *(const short8*)(vrow + 16 * ks + 8 * l5);

        for (int t = 0; t < 32; ++t) {
            block_sync_lds();
            const int pb = t & 1;
            const int kb0 = t * 128;
            // issue second-half V loads for THIS phase (consumed ~600cy later)
#pragma unroll
            for (int ks = 0; ks < 4; ++ks)
                vfB[ks] = *(const short8*)(vrow + kb0 + 64 + 16 * ks + 8 * l5);
            __builtin_amdgcn_s_setprio(1);
#pragma unroll
            for (int ks = 0; ks < 4; ++ks) {
                short8 pa[4];
#pragma unroll
                for (int st = 0; st < 4; ++st)
                    pa[st] = *(const short8*)&p_lds[pb][2 * ks + l5][32 * st + l31][0];
#pragma unroll
                for (int st = 0; st < 4; ++st)
                    acc[st] = __builtin_amdgcn_mfma_f32_32x32x16_bf16(pa[st], vfA[ks], acc[st], 0, 0, 0);
            }
            __builtin_amdgcn_s_setprio(0);
            // issue first-half V loads for NEXT phase
            const int nb = (t < 31) ? kb0 + 128 : 0;
#pragma unroll
            for (int ks = 0; ks < 4; ++ks)
                vfA[ks] = *(const short8*)(vrow + nb + 16 * ks + 8 * l5);
            __builtin_amdgcn_s_setprio(1);
#pragma unroll
            for (int ks = 4; ks < 8; ++ks) {
                short8 pa[4];
#pragma unroll
                for (int st = 0; st < 4; ++st)
                    pa[st] = *(const short8*)&p_lds[pb][2 * ks + l5][32 * st + l31][0];
#pragma unroll
                for (int st = 0; st < 4; ++st)
                    acc[st] = __builtin_amdgcn_mfma_f32_32x32x16_bf16(pa[st], vfB[ks - 4], acc[st], 0, 0, 0);
            }
            __builtin_amdgcn_s_setprio(0);
        }

        __syncthreads();   // wait for lsum_lds (producers' final write)

        // ---- epilogue: out = gamma*acc/lsum + x ----
        const float g = gamma[0];
#pragma unroll
        for (int st = 0; st < 4; ++st) {
#pragma unroll
            for (int rq = 0; rq < 4; ++rq) {
                int rbase = 32 * st + 8 * rq + 4 * l5;   // D row = (r&3)+8*(r>>2)+4*l5
                f32x4 ls = *(const f32x4*)&lsum_lds[rbase];
                f32x4 gi;
#pragma unroll
                for (int m = 0; m < 4; ++m) gi[m] = g / ls[m];
                size_t off = bx_base + (size_t)ch * 4096 + s0 + rbase;
                f32x4 xv = *(const f32x4*)(x + off);
                f32x4 o;
#pragma unroll
                for (int m = 0; m < 4; ++m)
                    o[m] = gi[m] * acc[st][4 * rq + m] + xv[m];
                *(f32x4*)(out + off) = o;
            }
        }
    }
}

// ---------------------------------------------------------------------------
extern "C" void kernel_launch(void* const* d_in, const int* in_sizes, int n_in,
                              void* d_out, int out_size, void* d_ws, size_t ws_size,
                              hipStream_t stream) {
    const float* x     = (const float*)d_in[0];
    const float* wqk   = (const float*)d_in[1];
    const float* wv    = (const float*)d_in[2];
    const float* gamma = (const float*)d_in[3];
    float* out = (float*)d_out;

    char* ws = (char*)d_ws;
    unsigned short* W    = (unsigned short*)(ws);                       // 160 KiB
    unsigned short* qkT  = (unsigned short*)(ws + 163840);              // 4 MiB
    unsigned short* xT   = (unsigned short*)(ws + 163840 + 4194304);    // 16 MiB
    unsigned short* vbuf = (unsigned short*)(ws + 163840 + 4194304 + 16777216); // 16 MiB

    hipLaunchKernelGGL(prep_w_kernel,    dim3(320),  dim3(256), 0, stream, wqk, wv, W);
    hipLaunchKernelGGL(transpose_kernel, dim3(2048), dim3(256), 0, stream, x, xT);
    hipLaunchKernelGGL(proj_kernel,      dim3(512),  dim3(256), 0, stream, W, xT, qkT, vbuf);
    hipLaunchKernelGGL(attn_kernel,      dim3(512),  dim3(512), 0, stream, qkT, vbuf, x, gamma, out);
}